// Round 8
// baseline (42.015 us; speedup 1.0000x reference)
//
#include <hip/hip_runtime.h>
#include <hip/hip_bf16.h>
#include <math.h>

// MultiVariateAttention: out[b,u] = exp(mvn_logpdf(x[b]; mu[u], diag(s[u])))
// B = U = 4096, D = 16, fp32 in/out.
//
// R8: fused single kernel, v2 (repairs R4's failure):
//  - 1D grid, uslice = bid & 7  ->  u-slice pinned to one XCD: attn-diag
//    lines fetched from HBM once per XCD slice (R4 refetched 17.6 MB).
//  - sum log2(s_d) = log2(prod s_d): ONE v_log_f32 per u (R4: 16/u).
//  - v_rcp_f32 for 1/s^2 (numerics headroom proven: R4 absmax 2.7e-20).
//  - all register arrays statically indexed; no (&v.x)[k] patterns.
//  - xs (LDS x-tile) loads issue first -> barrier waits only on them;
//    b-loop reads x from LDS (lgkmcnt) so output stores (vmcnt) are never
//    awaited in the loop and stream freely.

#define TPB 256
#define DD 16
#define UPT 2      // u's per thread
#define BPB 32     // b rows per block; grid = 1024 blocks = 4/CU
#define NSLICE 8   // U / (TPB*UPT) u-slices == XCD count

static constexpr float L2E   = 1.4426950408889634f;   // log2(e)
static constexpr float HL2PI = 0.91893853320467274f;  // 0.5*ln(2*pi)

__global__ __launch_bounds__(TPB, 4) void mva_fused2(
    const float* __restrict__ x,      // [B,1,D]
    const float* __restrict__ units,  // [U,D]
    const float* __restrict__ attn,   // [U,D,D]
    float* __restrict__ out, int U)
{
    const int bid    = blockIdx.x;
    const int uslice = bid & (NSLICE - 1);   // == XCD id under round-robin
    const int bchunk = bid >> 3;
    const int u0 = uslice * (TPB * UPT) + threadIdx.x * UPT;
    const int b0 = bchunk * BPB;

    // ---- stage x tile into LDS first (2 coalesced loads/thread) ----
    __shared__ float xs[BPB][DD];
    {
        int i0 = threadIdx.x, i1 = threadIdx.x + TPB;
        float v0 = x[(size_t)b0 * DD + i0];
        float v1 = x[(size_t)b0 * DD + i1];
        xs[i0 >> 4][i0 & 15] = v0;
        xs[i1 >> 4][i1 & 15] = v1;
    }

    // ---- per-thread params for UPT consecutive units (hw rcp + 1 hw log) ----
    float a1[UPT][DD], a2[UPT][DD], bias[UPT];
#pragma unroll
    for (int i = 0; i < UPT; ++i) {
        const int u = u0 + i;
        const float* ad = attn + (size_t)u * DD * DD;  // diag at d*(DD+1)
        const float* up = units + (size_t)u * DD;
        float mu[DD];
#pragma unroll
        for (int j = 0; j < 4; ++j) {
            float4 m = *reinterpret_cast<const float4*>(up + 4 * j);
            mu[4 * j + 0] = m.x; mu[4 * j + 1] = m.y;
            mu[4 * j + 2] = m.z; mu[4 * j + 3] = m.w;
        }
        float qn = 0.f, prod = 1.f;
#pragma unroll
        for (int d = 0; d < DD; ++d) {
            float s = fmaxf(ad[d * (DD + 1)], 1e-6f);
            float r = __builtin_amdgcn_rcpf(s);
            float w = r * r;
            float t = mu[d] * w;
            a1[i][d] = L2E * t;
            a2[i][d] = -0.5f * L2E * w;
            qn   = fmaf(mu[d], t, qn);
            prod *= s;
        }
        // bias = -0.5*L2E*qn - log2(prod) - D*L2E*0.5*ln(2pi)
        bias[i] = fmaf(-0.5f * L2E, qn,
                       -(__builtin_amdgcn_logf(prod) + DD * L2E * HL2PI));
    }
    __syncthreads();

    // ---- main loop: 32 b rows; x from LDS broadcast; stores stream ----
#pragma unroll 2
    for (int b = 0; b < BPB; ++b) {
        float acc0 = bias[0], acc1 = bias[1];
#pragma unroll
        for (int j = 0; j < 4; ++j) {
            float4 xv = *reinterpret_cast<const float4*>(&xs[b][4 * j]);
            const int d = 4 * j;
            float t;
            t = fmaf(xv.x, a2[0][d + 0], a1[0][d + 0]); acc0 = fmaf(xv.x, t, acc0);
            t = fmaf(xv.x, a2[1][d + 0], a1[1][d + 0]); acc1 = fmaf(xv.x, t, acc1);
            t = fmaf(xv.y, a2[0][d + 1], a1[0][d + 1]); acc0 = fmaf(xv.y, t, acc0);
            t = fmaf(xv.y, a2[1][d + 1], a1[1][d + 1]); acc1 = fmaf(xv.y, t, acc1);
            t = fmaf(xv.z, a2[0][d + 2], a1[0][d + 2]); acc0 = fmaf(xv.z, t, acc0);
            t = fmaf(xv.z, a2[1][d + 2], a1[1][d + 2]); acc1 = fmaf(xv.z, t, acc1);
            t = fmaf(xv.w, a2[0][d + 3], a1[0][d + 3]); acc0 = fmaf(xv.w, t, acc0);
            t = fmaf(xv.w, a2[1][d + 3], a1[1][d + 3]); acc1 = fmaf(xv.w, t, acc1);
        }
        float2 o;
        o.x = __builtin_amdgcn_exp2f(acc0);
        o.y = __builtin_amdgcn_exp2f(acc1);
        *reinterpret_cast<float2*>(out + (size_t)(b0 + b) * U + u0) = o;
    }
}

extern "C" void kernel_launch(void* const* d_in, const int* in_sizes, int n_in,
                              void* d_out, int out_size, void* d_ws, size_t ws_size,
                              hipStream_t stream) {
    const float* x     = (const float*)d_in[0];  // [B,1,D]
    const float* units = (const float*)d_in[1];  // [U,D]
    const float* attn  = (const float*)d_in[2];  // [U,D,D]
    float* out = (float*)d_out;

    const int B = in_sizes[0] / DD;  // 4096
    const int U = in_sizes[1] / DD;  // 4096

    const int nblk = (B / BPB) * (U / (TPB * UPT));  // 128 * 8 = 1024
    mva_fused2<<<nblk, TPB, 0, stream>>>(x, units, attn, out, U);
}

// Round 9
// 27.436 us; speedup vs baseline: 1.5314x; 1.5314x over previous
//
#include <hip/hip_runtime.h>
#include <hip/hip_bf16.h>
#include <math.h>

// MultiVariateAttention: out[b,u] = exp(mvn_logpdf(x[b]; mu[u], diag(s[u])))
// B = U = 4096, D = 16, fp32 in/out.
//
// R9 = R3 (best measured, 28.6us) + ONE lever: packed fp32 math in the
// b-loop (v_pk_fma_f32 via float2 ext-vectors). UPT=2 param layout is
// pack-native: P[d*U+u0] is exactly {a1(u0),a1(u0+1)}. Halves b-loop VALU
// issue (R8 counters: VALU ~12us co-binding with the 10.2us store floor).

#define TPB 256
#define DD 16
#define UPT 2      // u's per thread
#define BPB 32     // b rows per block -> grid 1024 = 4 blocks/CU

typedef float v2f __attribute__((ext_vector_type(2)));

static constexpr float L2E   = 1.4426950408889634f;   // log2(e)
static constexpr float HL2PI = 0.91893853320467274f;  // 0.5*ln(2*pi)

// P layout: [2*D+1][U]. rows 0..15 = A1[d], 16..31 = A2[d], 32 = bias.
__global__ __launch_bounds__(TPB) void mva_precompute(
    const float* __restrict__ units, const float* __restrict__ attn,
    float* __restrict__ P, int U)
{
    int g = blockIdx.x * TPB + threadIdx.x;
    int u = g >> 4, d = g & 15;
    float s  = fmaxf(attn[(size_t)u * DD * DD + d * (DD + 1)], 1e-6f);
    float w  = 1.f / (s * s);
    float mu = units[g];
    P[(size_t)d * U + u]        = L2E * mu * w;
    P[(size_t)(DD + d) * U + u] = -0.5f * L2E * w;
    float bn = -0.5f * mu * mu * w - logf(s);
    bn += __shfl_xor(bn, 1, 16);
    bn += __shfl_xor(bn, 2, 16);
    bn += __shfl_xor(bn, 4, 16);
    bn += __shfl_xor(bn, 8, 16);
    if (d == 0) P[(size_t)(2 * DD) * U + u] = L2E * (bn - DD * HL2PI);
}

template <bool USE_WS>
__global__ __launch_bounds__(TPB, 4) void mva_main(
    const float* __restrict__ x,      // [B,1,D]
    const float* __restrict__ P,      // [33][U] when USE_WS
    const float* __restrict__ units,  // raw params when !USE_WS
    const float* __restrict__ attn,
    float* __restrict__ out, int U)
{
    const int u0 = blockIdx.y * (TPB * UPT) + threadIdx.x * UPT;
    const int b0 = blockIdx.x * BPB;

    __shared__ float xs[BPB][DD];
    for (int idx = threadIdx.x; idx < BPB * DD; idx += TPB) {
        xs[idx >> 4][idx & 15] = x[(size_t)b0 * DD + idx];
    }

    // Packed params: a1p[d] = {a1(u0), a1(u0+1)}, etc.
    v2f a1p[DD], a2p[DD], biasp;
    if (USE_WS) {
#pragma unroll
        for (int d = 0; d < DD; ++d) {
            a1p[d] = *reinterpret_cast<const v2f*>(P + (size_t)d * U + u0);
            a2p[d] = *reinterpret_cast<const v2f*>(P + (size_t)(DD + d) * U + u0);
        }
        biasp = *reinterpret_cast<const v2f*>(P + (size_t)(2 * DD) * U + u0);
    } else {
#pragma unroll
        for (int i = 0; i < UPT; ++i) {
            int u = u0 + i;
            float bn = 0.f;
#pragma unroll
            for (int d = 0; d < DD; ++d) {
                float s  = fmaxf(attn[(size_t)u * DD * DD + d * (DD + 1)], 1e-6f);
                float w  = 1.f / (s * s);
                float mu = units[u * DD + d];
                a1p[d][i] = L2E * mu * w;
                a2p[d][i] = -0.5f * L2E * w;
                bn += -0.5f * mu * mu * w - logf(s);
            }
            biasp[i] = L2E * (bn - DD * HL2PI);
        }
    }
    __syncthreads();

#pragma unroll 2
    for (int b = 0; b < BPB; ++b) {
        v2f acc = biasp;
#pragma unroll
        for (int j = 0; j < 4; ++j) {
            // Wave-uniform LDS address -> broadcast, conflict-free.
            float4 xv = *reinterpret_cast<const float4*>(&xs[b][4 * j]);
            const int d = 4 * j;
            v2f xx, t;
            xx = (v2f){xv.x, xv.x};
            t   = __builtin_elementwise_fma(xx, a2p[d + 0], a1p[d + 0]);
            acc = __builtin_elementwise_fma(xx, t, acc);
            xx = (v2f){xv.y, xv.y};
            t   = __builtin_elementwise_fma(xx, a2p[d + 1], a1p[d + 1]);
            acc = __builtin_elementwise_fma(xx, t, acc);
            xx = (v2f){xv.z, xv.z};
            t   = __builtin_elementwise_fma(xx, a2p[d + 2], a1p[d + 2]);
            acc = __builtin_elementwise_fma(xx, t, acc);
            xx = (v2f){xv.w, xv.w};
            t   = __builtin_elementwise_fma(xx, a2p[d + 3], a1p[d + 3]);
            acc = __builtin_elementwise_fma(xx, t, acc);
        }
        float2 o;
        o.x = __builtin_amdgcn_exp2f(acc[0]);
        o.y = __builtin_amdgcn_exp2f(acc[1]);
        *reinterpret_cast<float2*>(out + (size_t)(b0 + b) * U + u0) = o;
    }
}

extern "C" void kernel_launch(void* const* d_in, const int* in_sizes, int n_in,
                              void* d_out, int out_size, void* d_ws, size_t ws_size,
                              hipStream_t stream) {
    const float* x     = (const float*)d_in[0];  // [B,1,D]
    const float* units = (const float*)d_in[1];  // [U,D]
    const float* attn  = (const float*)d_in[2];  // [U,D,D]
    float* out = (float*)d_out;

    const int B = in_sizes[0] / DD;  // 4096
    const int U = in_sizes[1] / DD;  // 4096

    dim3 grid(B / BPB, U / (TPB * UPT));  // (128, 8) = 1024 blocks
    size_t pbytes = (size_t)(2 * DD + 1) * U * sizeof(float);

    if (ws_size >= pbytes) {
        float* P = (float*)d_ws;
        mva_precompute<<<(U * DD) / TPB, TPB, 0, stream>>>(units, attn, P, U);
        mva_main<true><<<grid, TPB, 0, stream>>>(x, P, units, attn, out, U);
    } else {
        mva_main<false><<<grid, TPB, 0, stream>>>(x, nullptr, units, attn, out, U);
    }
}